// Round 7
// baseline (460.693 us; speedup 1.0000x reference)
//
#include <hip/hip_runtime.h>

#define BB 8
#define SS 16
#define HH 512
#define WW 512
#define HWP (HH*WW)

// workspace layout (float offsets)
#define WS_MSUM 0      // [8][16]
#define WS_FSUM 128    // [8][16][2]
#define WS_ACC  640    // num_s[16], l1x, l1y, l2x, l2y
#define WS_TOTAL 660

__device__ __forceinline__ float clip01(float x){ return fminf(fmaxf(x, 0.0f), 1.0f); }
__device__ __forceinline__ float pow045(float v){ return exp2f(0.45f * log2f(v)); }
__device__ __forceinline__ float cbn(float x){ return pow045(x*x + 1e-6f); }

typedef const __attribute__((address_space(1))) void* as1cv;
typedef __attribute__((address_space(3))) void* as3v;
__device__ __forceinline__ void gload16(const void* g, void* l){
    __builtin_amdgcn_global_load_lds((as1cv)g, (as3v)l, 16, 0, 0);
}

// ---------------- kernel A: mask sums + mask-weighted flow sums ----------------
// Double-buffered global_load_lds staging: 36KB tiles (16 masks x 2KB + flow 4KB).
// Loads go straight to LDS (no VGPR destinations) -> ~72KB outstanding per CU,
// far above the ~9.2KB needed to saturate HBM. m97 pattern:
// stage(t+1); compute(t); __syncthreads().
__global__ __launch_bounds__(256)
void kA(const float* __restrict__ flow, const float* __restrict__ masks,
        float* __restrict__ ws)
{
    const int b   = blockIdx.y;
    const int tb0 = blockIdx.x * 4096;          // 64 chunks of 4096 px
    const float* fU = flow + (size_t)b * 2 * HWP;
    const float* fV = fU + HWP;
    const float* mb = masks + (size_t)b * SS * HWP;

    __shared__ float buf[2][36*256];            // 2 x 36KB
    __shared__ float red[4][3*SS];

    const int wv = threadIdx.x >> 6, lane = threadIdx.x & 63;

    float am[SS], au[SS], av[SS];
#pragma unroll
    for (int s = 0; s < SS; ++s){ am[s]=0.f; au[s]=0.f; av[s]=0.f; }

    // stage tile t into buffer pb: 36 chunks of 256 floats; wave w does chunks w,w+4,...
    auto stage = [&](int t, int pb){
        const int tb = tb0 + t * 512;
        float* base = &buf[pb][0];
#pragma unroll
        for (int k = 0; k < 9; ++k){
            const int c = wv + 4*k;
            const float* src;
            if (c < 32)       src = mb + (size_t)(c>>1)*HWP + tb + (c&1)*256;
            else if (c < 34)  src = fU + tb + (c&1)*256;
            else              src = fV + tb + (c&1)*256;
            gload16(src + lane*4, base + c*256);
        }
    };

    auto compute = [&](int pb){
        const float* B = &buf[pb][0];
        const int t2 = threadIdx.x * 2;
        const float2 uu = *reinterpret_cast<const float2*>(B + 16*512 + t2);
        const float2 vv = *reinterpret_cast<const float2*>(B + 16*512 + 512 + t2);
#pragma unroll
        for (int s = 0; s < SS; ++s){
            const float2 m = *reinterpret_cast<const float2*>(B + s*512 + t2);
            am[s] += m.x + m.y;
            au[s] += m.x*uu.x + m.y*uu.y;
            av[s] += m.x*vv.x + m.y*vv.y;
        }
    };

    stage(0, 0);
    __syncthreads();                 // drain prologue stage
    for (int t = 0; t < 8; ++t){
        if (t < 7) stage(t+1, (t+1)&1);   // issue next tile (flies during compute)
        compute(t & 1);
        __syncthreads();             // drains vmcnt(0): next tile ready; readers done
    }

    // wave reduce 48 values, cross-wave via LDS, atomics
#pragma unroll
    for (int s = 0; s < SS; ++s){
#pragma unroll
        for (int o = 32; o > 0; o >>= 1){
            am[s] += __shfl_down(am[s], o, 64);
            au[s] += __shfl_down(au[s], o, 64);
            av[s] += __shfl_down(av[s], o, 64);
        }
    }
    if (lane == 0){
#pragma unroll
        for (int s = 0; s < SS; ++s){
            red[wv][s] = am[s]; red[wv][SS+s] = au[s]; red[wv][2*SS+s] = av[s];
        }
    }
    __syncthreads();
    if (threadIdx.x < 3*SS){
        const int i = threadIdx.x;
        const float t = red[0][i] + red[1][i] + red[2][i] + red[3][i];
        const int s = i % SS, kind = i / SS;
        if (kind == 0) atomicAdd(ws + WS_MSUM + b*SS + s, t);
        else           atomicAdd(ws + WS_FSUM + (b*SS + s)*2 + (kind-1), t);
    }
}

// ---------------- kernel C: direct-load fused pass (no LDS tiles, no barriers) ----------------
// Thread owns a vertical pixel pair (rows h0,h0+1 at col w). All neighborhoods
// loaded directly from global (clamped; zero-select for image) -> no barrier
// serialization; TLP hides latency. Mean-flow computed in prologue (kB folded in).
__global__ __launch_bounds__(256)
void kC(const float* __restrict__ flow, const float* __restrict__ image,
        const float* __restrict__ masks, float* __restrict__ ws)
{
    const int b  = blockIdx.z;
    const int tid = threadIdx.x;
    const int h0 = blockIdx.y*16 + ((tid>>5)<<1);
    const int w  = blockIdx.x*32 + (tid&31);

    __shared__ float sMean[2*SS];
    __shared__ float sRed[4][20];
    if (tid < 2*SS){
        const int s = tid >> 1;
        const float ms = fmaxf(ws[WS_MSUM + b*SS + s], 1e-6f);
        sMean[tid] = ws[WS_FSUM + (b*SS + s)*2 + (tid&1)] / ms;
    }
    __syncthreads();

    const int rA = max(h0-1, 0), rC = h0+1, rD = min(h0+2, HH-1);
    const int wm = max(w-1, 0),  wp = min(w+1, WW-1);
    const int oA = rA*WW, oB = h0*WW, oC = rC*WW, oD = rD*WW;

    const float* mb  = masks + (size_t)b * SS * HWP;
    const float* flo = flow  + (size_t)b * 2 * HWP;
    const float* img = image + (size_t)b * 3 * HWP;

    const float fu0 = flo[oB + w],       fu1 = flo[oC + w];
    const float fv0 = flo[HWP + oB + w], fv1 = flo[HWP + oC + w];

    float occ[12];
#pragma unroll
    for (int j = 0; j < 12; ++j) occ[j] = 0.f;
    float numv[SS];
    float perS0 = 0.f, perS1 = 0.f;

#pragma unroll
    for (int s = 0; s < SS; ++s){
        const float* M = mb + (size_t)s * HWP;
        const float mAm=M[oA+wm], mA0=M[oA+w], mAp=M[oA+wp];
        const float mBm=M[oB+wm], mB0=M[oB+w], mBp=M[oB+wp];
        const float mCm=M[oC+wm], mC0=M[oC+w], mCp=M[oC+wp];
        const float mDm=M[oD+wm], mD0=M[oD+w], mDp=M[oD+wp];
        occ[0]+=mAm; occ[1]+=mA0;  occ[2]+=mAp;
        occ[3]+=mBm; occ[4]+=mB0;  occ[5]+=mBp;
        occ[6]+=mCm; occ[7]+=mC0;  occ[8]+=mCp;
        occ[9]+=mDm; occ[10]+=mD0; occ[11]+=mDp;

        const float xm = fmaxf(mBm,mCm), x0 = fmaxf(mB0,mC0), xp = fmaxf(mBp,mCp);
        const float nm = fminf(mBm,mCm), n0 = fminf(mB0,mC0), np = fminf(mBp,mCp);
        const float rng0 = fmaxf(fmaxf(fmaxf(xm,mAm), fmaxf(x0,mA0)), fmaxf(xp,mAp))
                         - fminf(fminf(fminf(nm,mAm), fminf(n0,mA0)), fminf(np,mAp));
        const float rng1 = fmaxf(fmaxf(fmaxf(xm,mDm), fmaxf(x0,mD0)), fmaxf(xp,mDp))
                         - fminf(fminf(fminf(nm,mDm), fminf(n0,mD0)), fminf(np,mDp));
        perS0 += clip01(rng0);
        perS1 += clip01(rng1);

        const float mu = sMean[2*s], mv = sMean[2*s+1];
        const float d0u = fu0-mu, d0v = fv0-mv, d1u = fu1-mu, d1v = fv1-mv;
        numv[s] = pow045(d0u*d0u + d0v*d0v + 1e-6f)*mB0
                + pow045(d1u*d1u + d1v*d1v + 1e-6f)*mC0;
    }

    const float oxm = fmaxf(occ[3],occ[6]), ox0 = fmaxf(occ[4],occ[7]), oxp = fmaxf(occ[5],occ[8]);
    const float onm = fminf(occ[3],occ[6]), on0 = fminf(occ[4],occ[7]), onp = fminf(occ[5],occ[8]);
    const float org0 = fmaxf(fmaxf(fmaxf(oxm,occ[0]), fmaxf(ox0,occ[1])), fmaxf(oxp,occ[2]))
                     - fminf(fminf(fminf(onm,occ[0]), fminf(on0,occ[1])), fminf(onp,occ[2]));
    const float org1 = fmaxf(fmaxf(fmaxf(oxm,occ[9]), fmaxf(ox0,occ[10])), fmaxf(oxp,occ[11]))
                     - fminf(fminf(fminf(onm,occ[9]), fminf(on0,occ[10])), fminf(onp,occ[11]));
    const float bnd0 = clip01(clip01(org0) + perS0);
    const float bnd1 = clip01(clip01(org1) + perS1);

    // Sobel (zero padding via validity select)
    const bool vA = (h0 >= 1), vD = (h0+2 <= HH-1);
    const bool vm = (w  >= 1), vp = (w+1  <= WW-1);
    float mag0 = 0.f, mag1 = 0.f;
#pragma unroll
    for (int ch = 0; ch < 3; ++ch){
        const float* I = img + (size_t)ch * HWP;
        const float iAm = (vA&&vm) ? I[oA+wm] : 0.f;
        const float iA0 =  vA      ? I[oA+w ] : 0.f;
        const float iAp = (vA&&vp) ? I[oA+wp] : 0.f;
        const float iBm =  vm      ? I[oB+wm] : 0.f;
        const float iB0 =             I[oB+w ];
        const float iBp =  vp      ? I[oB+wp] : 0.f;
        const float iCm =  vm      ? I[oC+wm] : 0.f;
        const float iC0 =             I[oC+w ];
        const float iCp =  vp      ? I[oC+wp] : 0.f;
        const float iDm = (vD&&vm) ? I[oD+wm] : 0.f;
        const float iD0 =  vD      ? I[oD+w ] : 0.f;
        const float iDp = (vD&&vp) ? I[oD+wp] : 0.f;

        // px0: rows A,B,C
        const float gx0 = (iAm + 2.f*iBm + iCm) - (iAp + 2.f*iBp + iCp);
        const float gy0 = (iAm + 2.f*iA0 + iAp) - (iCm + 2.f*iC0 + iCp);
        mag0 += fabsf(gx0) + fabsf(gy0);
        // px1: rows B,C,D
        const float gx1 = (iBm + 2.f*iCm + iDm) - (iBp + 2.f*iCp + iDp);
        const float gy1 = (iBm + 2.f*iB0 + iBp) - (iDm + 2.f*iD0 + iDp);
        mag1 += fabsf(gx1) + fabsf(gy1);
    }
    mag0 *= (1.f/3.f); mag1 *= (1.f/3.f);
    const float wgt0 = expf(-10.f * mag0) * (1.f - 0.9f*bnd0);
    const float wgt1 = expf(-10.f * mag1) * (1.f - 0.9f*bnd1);

    // flow neighbors
    const float uBm = flo[oB+wm], vBm = flo[HWP+oB+wm];
    const float uBp = flo[oB+wp], vBp = flo[HWP+oB+wp];
    const float uCm = flo[oC+wm], vCm = flo[HWP+oC+wm];
    const float uCp = flo[oC+wp], vCp = flo[HWP+oC+wp];
    const float uA  = flo[oA+w ], vA_ = flo[HWP+oA+w ];
    const float uD  = flo[oD+w ], vD_ = flo[HWP+oD+w ];

    float l1x = 0.f, l1y = 0.f, l2x = 0.f, l2y = 0.f;

    if (w >= 1){
        l1x += 0.5f * (cbn(fu0 - uBm) + cbn(fv0 - vBm)) * wgt0;
        l1x += 0.5f * (cbn(fu1 - uCm) + cbn(fv1 - vCm)) * wgt1;
    }
    if (h0 >= 1) l1y += 0.5f * (cbn(fu0 - uA) + cbn(fv0 - vA_)) * wgt0;
    l1y += 0.5f * (cbn(fu1 - fu0) + cbn(fv1 - fv0)) * wgt1;   // row h0+1 >= 1 always
    if (w >= 1 && w <= WW-2){
        l2x += cbn(uBp - 2.f*fu0 + uBm) + cbn(vBp - 2.f*fv0 + vBm);
        l2x += cbn(uCp - 2.f*fu1 + uCm) + cbn(vCp - 2.f*fv1 + vCm);
    }
    if (h0 >= 1)        l2y += cbn(fu1 - 2.f*fu0 + uA) + cbn(fv1 - 2.f*fv0 + vA_);  // h0 in [1,510] (h0<=510 always)
    if (h0+1 <= HH-2)   l2y += cbn(uD - 2.f*fu1 + fu0) + cbn(vD_ - 2.f*fv1 + fv0);

    // block reduction of 20 values
    float vals[20];
#pragma unroll
    for (int s = 0; s < SS; ++s) vals[s] = numv[s];
    vals[16] = l1x; vals[17] = l1y; vals[18] = l2x; vals[19] = l2y;

    const int lane = tid & 63, wvv = tid >> 6;
#pragma unroll
    for (int i = 0; i < 20; ++i){
        float v = vals[i];
#pragma unroll
        for (int o = 32; o > 0; o >>= 1) v += __shfl_down(v, o, 64);
        if (lane == 0) sRed[wvv][i] = v;
    }
    __syncthreads();
    if (tid < 20){
        const float t = sRed[0][tid] + sRed[1][tid] + sRed[2][tid] + sRed[3][tid];
        atomicAdd(ws + WS_ACC + tid, t);
    }
}

// ---------------- finalize ----------------
__global__ void kF(const float* __restrict__ ws, float* __restrict__ out)
{
    __shared__ float sw[SS];
    const int t = threadIdx.x;
    if (t < SS){
        float w = 0.f;
        for (int b = 0; b < BB; ++b) w += fmaxf(ws[WS_MSUM + b*SS + t], 1e-6f);
        sw[t] = w;
    }
    __syncthreads();
    if (t == 0){
        float total = 0.f, tw = 0.f;
        for (int s = 0; s < SS; ++s){
            const float w = sw[s];
            total += (ws[WS_ACC + s] / fmaxf(w, 1e-6f)) * w;
            tw += w;
        }
        const float seg = (tw > 1e-6f) ? (total / tw) : 0.f;
        const float l1 = ws[WS_ACC+16] / (8.f*512.f*511.f) + ws[WS_ACC+17] / (8.f*511.f*512.f);
        const float l2 = ws[WS_ACC+18] / (8.f*2.f*512.f*510.f) + ws[WS_ACC+19] / (8.f*2.f*510.f*512.f);
        out[0] = 0.1f*seg + 0.15f*(l1 + 0.5f*l2);
    }
}

extern "C" void kernel_launch(void* const* d_in, const int* in_sizes, int n_in,
                              void* d_out, int out_size, void* d_ws, size_t ws_size,
                              hipStream_t stream)
{
    (void)in_sizes; (void)n_in; (void)out_size; (void)ws_size;
    const float* flow  = (const float*)d_in[0];
    const float* image = (const float*)d_in[1];
    const float* masks = (const float*)d_in[2];
    float* ws  = (float*)d_ws;
    float* out = (float*)d_out;

    (void)hipMemsetAsync(d_ws, 0, WS_TOTAL * sizeof(float), stream);

    dim3 gA(64, BB);             // 512 blocks = 2/CU, all resident
    kA<<<gA, 256, 0, stream>>>(flow, masks, ws);
    dim3 gC(WW/32, HH/16, BB);   // (16, 32, 8)
    kC<<<gC, 256, 0, stream>>>(flow, image, masks, ws);
    kF<<<1, 64, 0, stream>>>(ws, out);
}